// Round 7
// baseline (9249.187 us; speedup 1.0000x reference)
//
#include <hip/hip_runtime.h>
#include <cstdint>
#include <cstddef>

#define TT 8192
#define BB 32
#define HH 256
#define TC 512
#define NCH 16
#define NSLOT (NCH + 2)
#define CROWS (BB * TC)   // rows per chunk = 16384

typedef float f32x4v __attribute__((ext_vector_type(4)));

__device__ __forceinline__ float qz(float x){
  float wc = fminf(fmaxf(x, -1.f), 1.f);
  return rintf((wc + 1.f) * 15.5f) / 15.5f - 1.f;
}

// fast tanh: (e^{2x}-1)/(e^{2x}+1), clamped; rel err ~1e-7
__device__ __forceinline__ float ftanh(float s){
  float sc = fminf(fmaxf(s, -15.f), 15.f);
  float e = __expf(2.f * sc);
  return (e - 1.f) * __builtin_amdgcn_rcpf(e + 1.f);
}

// DPP all-lanes butterfly add helper (ctrl must be a literal)
#define DPPADD(v, ctrl) \
  (v) += __int_as_float(__builtin_amdgcn_update_dpp(0, __float_as_int(v), (ctrl), 0xF, 0xF, true))

// volatile asm global load: defines dst as an opaque asm output ->
// cannot be rematerialized or sunk into the loop by the compiler.
#define WLD(D, P, OFF) \
  asm volatile("global_load_dwordx4 %0, %1, off offset:" OFF : "=v"(D) : "v"(P))

// ---------------- weight quantization (only analog_linear weights) ----------------
__global__ void quant_all(
  const float* __restrict__ W1, const float* __restrict__ W2,
  const float* __restrict__ Wh1, const float* __restrict__ Wh2,
  const float* __restrict__ bih1, const float* __restrict__ bhh1,
  const float* __restrict__ bih2, const float* __restrict__ bhh2,
  float* qW1, float* qW2, float* qWh1, float* qWh2,
  float* bL1, float* bL2)
{
  int i = blockIdx.x * 256 + threadIdx.x;
  if (i < 576){ qW1[i] = qz(W1[i]); return; }   i -= 576;
  if (i < 2048){ qW2[i] = qz(W2[i]); return; }  i -= 2048;
  if (i < 32768){ qWh1[i] = qz(Wh1[i]); return; } i -= 32768;
  if (i < 128){ qWh2[i] = qz(Wh2[i]); return; }  i -= 128;
  if (i < 256){ bL1[i] = bih1[i] + bhh1[i]; return; } i -= 256;
  if (i < 256){ bL2[i] = bih2[i] + bhh2[i]; return; }
}

// ---------------- context MLP + layer0 time-invariant pre ----------------
__global__ void ctx_kernel(const float* __restrict__ x, const float* __restrict__ qW1,
  const float* __restrict__ b1, const float* __restrict__ qW2, const float* __restrict__ b2,
  const float* __restrict__ wih0, const float* __restrict__ bih0, const float* __restrict__ bhh0,
  float* __restrict__ cvec)
{
  __shared__ float rc[32][9];
  __shared__ float h1[32][64];
  __shared__ float ce[32][32];
  int tid = threadIdx.x;
  for (int i = tid; i < 288; i += 256){
    int b = i / 9, j = i % 9;
    rc[b][j] = x[(size_t)b * TT * 10 + 1 + j];
  }
  __syncthreads();
  for (int i = tid; i < 2048; i += 256){
    int b = i >> 6, o = i & 63;
    float s = b1[o];
    #pragma unroll
    for (int j = 0; j < 9; ++j) s = fmaf(rc[b][j], qW1[o*9 + j], s);
    h1[b][o] = fmaxf(s, 0.f);
  }
  __syncthreads();
  for (int i = tid; i < 1024; i += 256){
    int b = i >> 5, o = i & 31;
    float s = b2[o];
    #pragma unroll
    for (int j = 0; j < 64; ++j) s = fmaf(h1[b][j], qW2[o*64 + j], s);
    ce[b][o] = tanhf(s);
  }
  __syncthreads();
  for (int i = tid; i < 8192; i += 256){
    int b = i >> 8, o = i & 255;
    float s = bih0[o] + bhh0[o];
    #pragma unroll
    for (int j = 0; j < 32; ++j) s = fmaf(ce[b][j], wih0[o*33 + 1 + j], s);
    cvec[i] = s;
  }
}

// ---------------- fused 3-layer pipelined scan ----------------
// 96 WGs: [0,32) layer0 chunk=slot, [32,64) layer1 chunk=slot-1, [64,96) layer2 chunk=slot-2.
// Thread (og=tid>>4, kc=tid&15): 8 outputs og*8+j, k-slice kc*16..+15.
// amdgpu_waves_per_eu(2,2): pins occupancy target = 2 waves/EU so the RA gets the
// full 256-VGPR budget and KEEPS the 128 weights in arch VGPRs (rounds 4-6 showed
// the scheduler targeting 6 waves/EU and AGPR-spilling them -> 128 v_accvgpr_read
// per step = the whole perf gap).
__global__ __attribute__((amdgpu_waves_per_eu(2, 2))) __launch_bounds__(512) void scan3(
  const float* __restrict__ whh0, const float* __restrict__ whh1, const float* __restrict__ whh2,
  const float* __restrict__ pre1, const float* __restrict__ pre2,
  const float* __restrict__ x, const float* __restrict__ cvec, const float* __restrict__ wih0,
  float* __restrict__ out0, float* __restrict__ out1, float* __restrict__ out2,
  float* __restrict__ hst0, float* __restrict__ hst1, float* __restrict__ hst2,
  int slot)
{
  __shared__ float hbuf[2][HH];
  const int layer = blockIdx.x >> 5;
  const int b = blockIdx.x & 31;
  const int c = slot - layer;
  if (c < 0 || c >= NCH) return;

  const float* whh = (layer == 0) ? whh0 : (layer == 1) ? whh1 : whh2;
  const float* pre = (layer == 1) ? pre1 : pre2;
  float* out = (layer == 0) ? out0 : (layer == 1) ? out1 : out2;
  float* hst = (layer == 0) ? hst0 : (layer == 1) ? hst1 : hst2;
  const int t0 = c * TC;

  const int tid = threadIdx.x;
  const int og = tid >> 4;
  const int kc = tid & 15;
  const int jm = kc & 7;
  const int o_mine = og * 8 + jm;

  // ---- 128 recurrent weights -> VGPRs via volatile asm loads (row stride 1KB) ----
  f32x4v wv[8][4];
  {
    const float* bp0 = whh + (size_t)(og * 8) * HH + (kc << 4);
    const float* bp1 = bp0 + 4 * HH;
    WLD(wv[0][0], bp0, "0");    WLD(wv[0][1], bp0, "16");   WLD(wv[0][2], bp0, "32");   WLD(wv[0][3], bp0, "48");
    WLD(wv[1][0], bp0, "1024"); WLD(wv[1][1], bp0, "1040"); WLD(wv[1][2], bp0, "1056"); WLD(wv[1][3], bp0, "1072");
    WLD(wv[2][0], bp0, "2048"); WLD(wv[2][1], bp0, "2064"); WLD(wv[2][2], bp0, "2080"); WLD(wv[2][3], bp0, "2096");
    WLD(wv[3][0], bp0, "3072"); WLD(wv[3][1], bp0, "3088"); WLD(wv[3][2], bp0, "3104"); WLD(wv[3][3], bp0, "3120");
    WLD(wv[4][0], bp1, "0");    WLD(wv[4][1], bp1, "16");   WLD(wv[4][2], bp1, "32");   WLD(wv[4][3], bp1, "48");
    WLD(wv[5][0], bp1, "1024"); WLD(wv[5][1], bp1, "1040"); WLD(wv[5][2], bp1, "1056"); WLD(wv[5][3], bp1, "1072");
    WLD(wv[6][0], bp1, "2048"); WLD(wv[6][1], bp1, "2064"); WLD(wv[6][2], bp1, "2080"); WLD(wv[6][3], bp1, "2096");
    WLD(wv[7][0], bp1, "3072"); WLD(wv[7][1], bp1, "3088"); WLD(wv[7][2], bp1, "3104"); WLD(wv[7][3], bp1, "3120");
    asm volatile("s_waitcnt vmcnt(0)" ::: "memory");
    __builtin_amdgcn_sched_barrier(0);
  }

  // h init into buf0
  if (tid < HH){
    hbuf[0][tid] = (c == 0) ? 0.f : hst[(size_t)b * HH + tid];
  }

  // first pre for my output
  float w0c = 0.f, cv = 0.f, pre_c;
  if (layer == 0){
    w0c = wih0[o_mine * 33];
    cv  = cvec[(size_t)b * HH + o_mine];
    pre_c = x[((size_t)b * TT + t0) * 10] * w0c + cv;
  } else {
    pre_c = pre[(size_t)(b * TC) * HH + o_mine];
  }
  __syncthreads();

  float hn = 0.f;
  for (int tl = 0; tl < TC; ++tl){
    // issue next-step pre load first: latency hides under the FMA phase
    int tn = (tl + 1 < TC) ? (tl + 1) : tl;
    float pre_n;
    if (layer == 0){
      pre_n = x[((size_t)b * TT + t0 + tn) * 10] * w0c + cv;
    } else {
      pre_n = pre[(size_t)(b * TC + tn) * HH + o_mine];
    }

    // h slice (16 floats) from LDS
    float hv[16];
    {
      const float* hb = hbuf[tl & 1] + kc * 16;
      #pragma unroll
      for (int m = 0; m < 4; ++m){
        float4 v = *(const float4*)(hb + m*4);
        hv[m*4+0] = v.x; hv[m*4+1] = v.y; hv[m*4+2] = v.z; hv[m*4+3] = v.w;
      }
    }

    // 8 partial dots (128 FMA)
    float acc[8];
    #pragma unroll
    for (int j = 0; j < 8; ++j){
      float s0 = 0.f, s1 = 0.f, s2 = 0.f, s3 = 0.f;
      #pragma unroll
      for (int m = 0; m < 4; ++m){
        s0 = fmaf(wv[j][m][0], hv[m*4+0], s0);
        s1 = fmaf(wv[j][m][1], hv[m*4+1], s1);
        s2 = fmaf(wv[j][m][2], hv[m*4+2], s2);
        s3 = fmaf(wv[j][m][3], hv[m*4+3], s3);
      }
      acc[j] = (s0 + s1) + (s2 + s3);
    }

    // butterfly allreduce across the 16 kc lanes: all lanes end with full sums
    #pragma unroll
    for (int j = 0; j < 8; ++j){
      float v = acc[j];
      DPPADD(v, 0xB1);   // quad_perm [1,0,3,2]  (xor 1)
      DPPADD(v, 0x4E);   // quad_perm [2,3,0,1]  (xor 2)
      DPPADD(v, 0x124);  // row_ror:4
      DPPADD(v, 0x128);  // row_ror:8
      acc[j] = v;
    }

    // select my output's sum (static-index cndmask chain)
    float s = acc[0];
    s = (jm == 1) ? acc[1] : s;
    s = (jm == 2) ? acc[2] : s;
    s = (jm == 3) ? acc[3] : s;
    s = (jm == 4) ? acc[4] : s;
    s = (jm == 5) ? acc[5] : s;
    s = (jm == 6) ? acc[6] : s;
    s = (jm == 7) ? acc[7] : s;
    s += pre_c;
    hn = ftanh(s);
    if (kc < 8){
      hbuf[(tl & 1) ^ 1][o_mine] = hn;
      out[(size_t)(b * TC + tl) * HH + o_mine] = hn;
    }
    pre_c = pre_n;
    __syncthreads();
  }
  if (kc < 8) hst[(size_t)b * HH + o_mine] = hn;
}

// ---------------- tiled fp32 GEMM tile (128x128, K=256) ----------------
__device__ __forceinline__ void gemm_tile(
  const float* __restrict__ A, const float* __restrict__ Bw,
  const float* __restrict__ bias, float* __restrict__ C,
  int bx, int by)
{
  __shared__ float As[16][132];
  __shared__ float Bs[16][132];
  const int tid = threadIdx.x;
  const int tx = tid & 15, ty = tid >> 4;
  const size_t n0 = (size_t)bx * 128;
  const int c0 = by * 128;
  float acc[8][8];
  #pragma unroll
  for (int i = 0; i < 8; ++i)
    #pragma unroll
    for (int j = 0; j < 8; ++j) acc[i][j] = 0.f;

  for (int k0 = 0; k0 < 256; k0 += 16){
    #pragma unroll
    for (int q = 0; q < 2; ++q){
      int f = tid + q*256;
      int row = f >> 2, k4 = f & 3;
      float4 va = *(const float4*)(A + (n0 + row)*256 + k0 + k4*4);
      As[k4*4+0][row] = va.x; As[k4*4+1][row] = va.y; As[k4*4+2][row] = va.z; As[k4*4+3][row] = va.w;
      float4 vb = *(const float4*)(Bw + (size_t)(c0 + row)*256 + k0 + k4*4);
      Bs[k4*4+0][row] = vb.x; Bs[k4*4+1][row] = vb.y; Bs[k4*4+2][row] = vb.z; Bs[k4*4+3][row] = vb.w;
    }
    __syncthreads();
    #pragma unroll
    for (int k = 0; k < 16; ++k){
      float a[8], bb[8];
      *(float4*)&a[0]  = *(const float4*)&As[k][ty*4];
      *(float4*)&a[4]  = *(const float4*)&As[k][ty*4 + 64];
      *(float4*)&bb[0] = *(const float4*)&Bs[k][tx*4];
      *(float4*)&bb[4] = *(const float4*)&Bs[k][tx*4 + 64];
      #pragma unroll
      for (int i = 0; i < 8; ++i)
        #pragma unroll
        for (int j = 0; j < 8; ++j) acc[i][j] = fmaf(a[i], bb[j], acc[i][j]);
    }
    __syncthreads();
  }
  #pragma unroll
  for (int i = 0; i < 8; ++i){
    size_t row = n0 + (size_t)ty*4 + (i & 3) + (i >> 2)*64;
    #pragma unroll
    for (int jh = 0; jh < 2; ++jh){
      int col = c0 + tx*4 + jh*64;
      float4 v;
      v.x = acc[i][jh*4+0] + bias[col+0];
      v.y = acc[i][jh*4+1] + bias[col+1];
      v.z = acc[i][jh*4+2] + bias[col+2];
      v.w = acc[i][jh*4+3] + bias[col+3];
      *(float4*)(C + row * 256 + col) = v;
    }
  }
}

// ---------------- head tile: gelu(A@qWh1^T + bh1) @ qWh2 + bh2 -> y ----------------
__device__ __forceinline__ void head_tile(
  const float* __restrict__ A, const float* __restrict__ Bw,
  const float* __restrict__ bh1, const float* __restrict__ w2,
  const float* __restrict__ bh2, float* __restrict__ y,
  int bx, int c2)
{
  __shared__ float As[16][132];
  __shared__ float Bs[16][132];
  const int tid = threadIdx.x;
  const int tx = tid & 15, ty = tid >> 4;
  const size_t n0 = (size_t)bx * 128;
  float acc[8][8];
  #pragma unroll
  for (int i = 0; i < 8; ++i)
    #pragma unroll
    for (int j = 0; j < 8; ++j) acc[i][j] = 0.f;

  for (int k0 = 0; k0 < 256; k0 += 16){
    #pragma unroll
    for (int q = 0; q < 2; ++q){
      int f = tid + q*256;
      int row = f >> 2, k4 = f & 3;
      float4 va = *(const float4*)(A + (n0 + row)*256 + k0 + k4*4);
      As[k4*4+0][row] = va.x; As[k4*4+1][row] = va.y; As[k4*4+2][row] = va.z; As[k4*4+3][row] = va.w;
      float4 vb = *(const float4*)(Bw + (size_t)row*256 + k0 + k4*4);   // 128 rows
      Bs[k4*4+0][row] = vb.x; Bs[k4*4+1][row] = vb.y; Bs[k4*4+2][row] = vb.z; Bs[k4*4+3][row] = vb.w;
    }
    __syncthreads();
    #pragma unroll
    for (int k = 0; k < 16; ++k){
      float a[8], bb[8];
      *(float4*)&a[0]  = *(const float4*)&As[k][ty*4];
      *(float4*)&a[4]  = *(const float4*)&As[k][ty*4 + 64];
      *(float4*)&bb[0] = *(const float4*)&Bs[k][tx*4];
      *(float4*)&bb[4] = *(const float4*)&Bs[k][tx*4 + 64];
      #pragma unroll
      for (int i = 0; i < 8; ++i)
        #pragma unroll
        for (int j = 0; j < 8; ++j) acc[i][j] = fmaf(a[i], bb[j], acc[i][j]);
    }
    __syncthreads();
  }
  float4 w2a = *(const float4*)(w2 + tx*4);
  float4 w2b = *(const float4*)(w2 + tx*4 + 64);
  const float bias2 = bh2[0];
  #pragma unroll
  for (int i = 0; i < 8; ++i){
    float p = 0.f;
    #pragma unroll
    for (int j = 0; j < 4; ++j){
      float g0 = acc[i][j]   + bh1[tx*4 + j];
      float g1 = acc[i][4+j] + bh1[tx*4 + 64 + j];
      g0 = 0.5f * g0 * (1.f + erff(g0 * 0.70710678118654752f));
      g1 = 0.5f * g1 * (1.f + erff(g1 * 0.70710678118654752f));
      p = fmaf(g0, ((const float*)&w2a)[j], p);
      p = fmaf(g1, ((const float*)&w2b)[j], p);
    }
    // reduce across the 16 tx lanes (row_shr chain); total at tx==15
    p += __int_as_float(__builtin_amdgcn_update_dpp(0, __float_as_int(p), 0x111, 0xF, 0xF, true));
    p += __int_as_float(__builtin_amdgcn_update_dpp(0, __float_as_int(p), 0x112, 0xF, 0xF, true));
    p += __int_as_float(__builtin_amdgcn_update_dpp(0, __float_as_int(p), 0x114, 0xF, 0xF, true));
    p += __int_as_float(__builtin_amdgcn_update_dpp(0, __float_as_int(p), 0x118, 0xF, 0xF, true));
    if (tx == 15){
      size_t n = n0 + (size_t)ty*4 + (i & 3) + (i >> 2)*64;
      int bsm = (int)(n >> 9);
      int tl  = (int)(n & (TC - 1));
      y[(size_t)bsm * TT + c2 * TC + tl] = p + bias2;
    }
  }
}

// ---------------- per-slot aux: gemm1 + gemm2 + head (fused GEMV) ----------------
__global__ __launch_bounds__(256) void aux_kernel(
  const float* __restrict__ out0, const float* __restrict__ out1, const float* __restrict__ out2,
  const float* __restrict__ wih1, const float* __restrict__ bL1, float* __restrict__ pre1,
  const float* __restrict__ wih2, const float* __restrict__ bL2, float* __restrict__ pre2,
  const float* __restrict__ qWh1, const float* __restrict__ bh1,
  const float* __restrict__ qWh2, const float* __restrict__ bh2,
  float* __restrict__ y, int slot)
{
  const int bid = blockIdx.x;
  if (bid < 512){
    int sec = bid >> 8;          // 0: pre1 from out0; 1: pre2 from out1
    int c = slot - sec;
    if (c < 0 || c >= NCH) return;
    int t = bid & 255;
    if (sec == 0) gemm_tile(out0, wih1, bL1, pre1, t >> 1, t & 1);
    else          gemm_tile(out1, wih2, bL2, pre2, t >> 1, t & 1);
  } else {
    int c2 = slot - 2;
    if (c2 < 0 || c2 >= NCH) return;
    head_tile(out2, qWh1, bh1, qWh2, bh2, y, bid - 512, c2);
  }
}

extern "C" void kernel_launch(void* const* d_in, const int* in_sizes, int n_in,
                              void* d_out, int out_size, void* d_ws, size_t ws_size,
                              hipStream_t stream)
{
  const float* x    = (const float*)d_in[0];
  const float* W1   = (const float*)d_in[1];
  const float* b1   = (const float*)d_in[2];
  const float* W2   = (const float*)d_in[3];
  const float* b2   = (const float*)d_in[4];
  const float* wih0 = (const float*)d_in[5];
  const float* whh0 = (const float*)d_in[6];
  const float* bih0 = (const float*)d_in[7];
  const float* bhh0 = (const float*)d_in[8];
  const float* wih1 = (const float*)d_in[9];
  const float* whh1 = (const float*)d_in[10];
  const float* bih1 = (const float*)d_in[11];
  const float* bhh1 = (const float*)d_in[12];
  const float* wih2 = (const float*)d_in[13];
  const float* whh2 = (const float*)d_in[14];
  const float* bih2 = (const float*)d_in[15];
  const float* bhh2 = (const float*)d_in[16];
  const float* Wh1  = (const float*)d_in[17];
  const float* bh1  = (const float*)d_in[18];
  const float* Wh2  = (const float*)d_in[19];
  const float* bh2  = (const float*)d_in[20];
  float* y = (float*)d_out;
  (void)in_sizes; (void)n_in; (void)out_size; (void)ws_size;

  char* p = (char*)d_ws;
  auto alloc = [&](size_t nfloats) -> float* {
    float* r = (float*)p;
    p += ((nfloats * sizeof(float) + 255) & ~(size_t)255);
    return r;
  };
  float* qW1  = alloc(576);
  float* qW2  = alloc(2048);
  float* qWh1 = alloc(32768);
  float* qWh2 = alloc(128);
  float* bL1  = alloc(256);
  float* bL2  = alloc(256);
  float* cvec = alloc((size_t)BB * HH);
  float* hst0 = alloc((size_t)BB * HH);
  float* hst1 = alloc((size_t)BB * HH);
  float* hst2 = alloc((size_t)BB * HH);
  float* out0 = alloc((size_t)CROWS * HH);
  float* out1 = alloc((size_t)CROWS * HH);
  float* out2 = alloc((size_t)CROWS * HH);
  float* pre1 = alloc((size_t)CROWS * HH);
  float* pre2 = alloc((size_t)CROWS * HH);

  quant_all<<<141, 256, 0, stream>>>(W1, W2, Wh1, Wh2,
                                     bih1, bhh1, bih2, bhh2,
                                     qW1, qW2, qWh1, qWh2, bL1, bL2);
  ctx_kernel<<<1, 256, 0, stream>>>(x, qW1, b1, qW2, b2, wih0, bih0, bhh0, cvec);

  for (int s = 0; s < NSLOT; ++s){
    scan3<<<96, 512, 0, stream>>>(whh0, whh1, whh2, pre1, pre2, x, cvec, wih0,
                                  out0, out1, out2, hst0, hst1, hst2, s);
    aux_kernel<<<640, 256, 0, stream>>>(out0, out1, out2,
                                        wih1, bL1, pre1,
                                        wih2, bL2, pre2,
                                        qWh1, bh1, qWh2, bh2, y, s);
  }
}

// Round 9
// 8852.311 us; speedup vs baseline: 1.0448x; 1.0448x over previous
//
#include <hip/hip_runtime.h>
#include <cstdint>
#include <cstddef>

#define TT 8192
#define BB 32
#define HH 256
#define TC 512
#define NCH 16
#define NSLOT (NCH + 2)
#define CROWS (BB * TC)   // rows per chunk = 16384

__device__ __forceinline__ float qz(float x){
  float wc = fminf(fmaxf(x, -1.f), 1.f);
  return rintf((wc + 1.f) * 15.5f) / 15.5f - 1.f;
}

// fast tanh: (e^{2x}-1)/(e^{2x}+1), clamped; rel err ~1e-7
__device__ __forceinline__ float ftanh(float s){
  float sc = fminf(fmaxf(s, -15.f), 15.f);
  float e = __expf(2.f * sc);
  return (e - 1.f) * __builtin_amdgcn_rcpf(e + 1.f);
}

// DPP all-lanes butterfly add helper (ctrl must be a literal)
#define DPPADD(v, ctrl) \
  (v) += __int_as_float(__builtin_amdgcn_update_dpp(0, __float_as_int(v), (ctrl), 0xF, 0xF, true))

// LDS word-index swizzle: 16B granule g -> g ^ (g>>3) (involution, bijective on [0,64))
// kills the 64B-stride 8-way bank conflict of ds_read_b128 (2-way max after).
__device__ __forceinline__ int swz(int o){
  int g = o >> 2;
  int gs = g ^ (g >> 3);
  return gs * 4 + (o & 3);
}

// ---------------- weight quantization (only analog_linear weights) ----------------
__global__ void quant_all(
  const float* __restrict__ W1, const float* __restrict__ W2,
  const float* __restrict__ Wh1, const float* __restrict__ Wh2,
  const float* __restrict__ bih1, const float* __restrict__ bhh1,
  const float* __restrict__ bih2, const float* __restrict__ bhh2,
  float* qW1, float* qW2, float* qWh1, float* qWh2,
  float* bL1, float* bL2)
{
  int i = blockIdx.x * 256 + threadIdx.x;
  if (i < 576){ qW1[i] = qz(W1[i]); return; }   i -= 576;
  if (i < 2048){ qW2[i] = qz(W2[i]); return; }  i -= 2048;
  if (i < 32768){ qWh1[i] = qz(Wh1[i]); return; } i -= 32768;
  if (i < 128){ qWh2[i] = qz(Wh2[i]); return; }  i -= 128;
  if (i < 256){ bL1[i] = bih1[i] + bhh1[i]; return; } i -= 256;
  if (i < 256){ bL2[i] = bih2[i] + bhh2[i]; return; }
}

// ---------------- context MLP + layer0 time-invariant pre ----------------
__global__ void ctx_kernel(const float* __restrict__ x, const float* __restrict__ qW1,
  const float* __restrict__ b1, const float* __restrict__ qW2, const float* __restrict__ b2,
  const float* __restrict__ wih0, const float* __restrict__ bih0, const float* __restrict__ bhh0,
  float* __restrict__ cvec)
{
  __shared__ float rc[32][9];
  __shared__ float h1[32][64];
  __shared__ float ce[32][32];
  int tid = threadIdx.x;
  for (int i = tid; i < 288; i += 256){
    int b = i / 9, j = i % 9;
    rc[b][j] = x[(size_t)b * TT * 10 + 1 + j];
  }
  __syncthreads();
  for (int i = tid; i < 2048; i += 256){
    int b = i >> 6, o = i & 63;
    float s = b1[o];
    #pragma unroll
    for (int j = 0; j < 9; ++j) s = fmaf(rc[b][j], qW1[o*9 + j], s);
    h1[b][o] = fmaxf(s, 0.f);
  }
  __syncthreads();
  for (int i = tid; i < 1024; i += 256){
    int b = i >> 5, o = i & 31;
    float s = b2[o];
    #pragma unroll
    for (int j = 0; j < 64; ++j) s = fmaf(h1[b][j], qW2[o*64 + j], s);
    ce[b][o] = tanhf(s);
  }
  __syncthreads();
  for (int i = tid; i < 8192; i += 256){
    int b = i >> 8, o = i & 255;
    float s = bih0[o] + bhh0[o];
    #pragma unroll
    for (int j = 0; j < 32; ++j) s = fmaf(ce[b][j], wih0[o*33 + 1 + j], s);
    cvec[i] = s;
  }
}

// ---------------- fused 3-layer pipelined scan ----------------
// 96 WGs x 1024 threads: [0,32) layer0 chunk=slot, [32,64) layer1 chunk=slot-1,
// [64,96) layer2 chunk=slot-2.
// Thread (og=tid>>4, kc=tid&15): 4 outputs og*4+j, k-slice kc*16..+15 ->
// 64 weights/thread = 64 VGPRs; total need ~105 fits the 128-reg budget at
// 4 waves/EU (amdgpu_waves_per_eu(4,4)) -> NO spill, NO per-step weight traffic.
// (Rounds 4-7: 128 w/thread @512thr always spilled -> 256KB/step L2 stream = bound.)
// h double-buffered in LDS with granule XOR-swizzle (conflict-free b128 reads).
// Reduce: 4-step DPP butterfly over the 16 kc lanes; select jm=kc&3; 1 barrier/step.
__global__ __attribute__((amdgpu_waves_per_eu(4, 4))) __launch_bounds__(1024) void scan3(
  const float* __restrict__ whh0, const float* __restrict__ whh1, const float* __restrict__ whh2,
  const float* __restrict__ pre1, const float* __restrict__ pre2,
  const float* __restrict__ x, const float* __restrict__ cvec, const float* __restrict__ wih0,
  float* __restrict__ out0, float* __restrict__ out1, float* __restrict__ out2,
  float* __restrict__ hst0, float* __restrict__ hst1, float* __restrict__ hst2,
  int slot)
{
  __shared__ float4 hb4[128];          // 2 x 256 floats, 16B-aligned
  float* hbuf = (float*)hb4;
  const int layer = blockIdx.x >> 5;
  const int b = blockIdx.x & 31;
  const int c = slot - layer;
  if (c < 0 || c >= NCH) return;

  const float* whh = (layer == 0) ? whh0 : (layer == 1) ? whh1 : whh2;
  const float* pre = (layer == 1) ? pre1 : pre2;
  float* out = (layer == 0) ? out0 : (layer == 1) ? out1 : out2;
  float* hst = (layer == 0) ? hst0 : (layer == 1) ? hst1 : hst2;
  const int t0 = c * TC;

  const int tid = threadIdx.x;
  const int og = tid >> 4;          // 64 output groups of 4
  const int kc = tid & 15;          // 16 k-chunks of 16
  const int jm = kc & 3;
  const int o_mine = og * 4 + jm;

  // ---- 64 recurrent weights -> VGPRs as scalars (fits budget; no spill pressure) ----
  float w[4][16];
  {
    const float* wr = whh + (size_t)(og * 4) * HH + (kc << 4);
    #pragma unroll
    for (int j = 0; j < 4; ++j){
      #pragma unroll
      for (int m = 0; m < 4; ++m){
        float4 v = *(const float4*)(wr + (size_t)j * HH + m * 4);
        w[j][m*4+0] = v.x; w[j][m*4+1] = v.y; w[j][m*4+2] = v.z; w[j][m*4+3] = v.w;
      }
    }
  }
  // one-time materialization pin (scalar operands only -- float4 ties don't compile)
  #pragma unroll
  for (int j = 0; j < 4; ++j){
    asm volatile("" :
      "+v"(w[j][0]),  "+v"(w[j][1]),  "+v"(w[j][2]),  "+v"(w[j][3]),
      "+v"(w[j][4]),  "+v"(w[j][5]),  "+v"(w[j][6]),  "+v"(w[j][7]),
      "+v"(w[j][8]),  "+v"(w[j][9]),  "+v"(w[j][10]), "+v"(w[j][11]),
      "+v"(w[j][12]), "+v"(w[j][13]), "+v"(w[j][14]), "+v"(w[j][15]));
  }

  // precomputed swizzled LDS read offsets (word units) for my 4 granules
  int rdw[4];
  #pragma unroll
  for (int m = 0; m < 4; ++m){
    int q = kc * 4 + m;
    rdw[m] = (q ^ (q >> 3)) * 4;
  }
  const int wrw = swz(o_mine);      // swizzled write word for my output

  // h init into buf0 (swizzled)
  if (tid < HH){
    hbuf[swz(tid)] = (c == 0) ? 0.f : hst[(size_t)b * HH + tid];
  }

  // first pre for my output
  float w0c = 0.f, cv = 0.f, pre_c;
  if (layer == 0){
    w0c = wih0[o_mine * 33];
    cv  = cvec[(size_t)b * HH + o_mine];
    pre_c = x[((size_t)b * TT + t0) * 10] * w0c + cv;
  } else {
    pre_c = pre[(size_t)(b * TC) * HH + o_mine];
  }
  __syncthreads();

  float hn = 0.f;
  for (int tl = 0; tl < TC; ++tl){
    // issue next-step pre load first: latency hides under the FMA phase
    int tn = (tl + 1 < TC) ? (tl + 1) : tl;
    float pre_n;
    if (layer == 0){
      pre_n = x[((size_t)b * TT + t0 + tn) * 10] * w0c + cv;
    } else {
      pre_n = pre[(size_t)(b * TC + tn) * HH + o_mine];
    }

    // h slice (16 floats) from swizzled LDS, conflict-free b128 reads
    const int rbase = (tl & 1) << 8;
    float4 hv[4];
    #pragma unroll
    for (int m = 0; m < 4; ++m)
      hv[m] = *(const float4*)&hbuf[rbase + rdw[m]];

    // 4 dots of 16 (64 FMA)
    float acc[4];
    #pragma unroll
    for (int j = 0; j < 4; ++j){
      float a0 = 0.f, a1 = 0.f, a2 = 0.f, a3 = 0.f;
      #pragma unroll
      for (int m = 0; m < 4; ++m){
        a0 = fmaf(w[j][m*4+0], hv[m].x, a0);
        a1 = fmaf(w[j][m*4+1], hv[m].y, a1);
        a2 = fmaf(w[j][m*4+2], hv[m].z, a2);
        a3 = fmaf(w[j][m*4+3], hv[m].w, a3);
      }
      acc[j] = (a0 + a1) + (a2 + a3);
    }

    // butterfly allreduce across the 16 kc lanes
    #pragma unroll
    for (int j = 0; j < 4; ++j){
      float v = acc[j];
      DPPADD(v, 0xB1);   // quad_perm [1,0,3,2]  (xor 1)
      DPPADD(v, 0x4E);   // quad_perm [2,3,0,1]  (xor 2)
      DPPADD(v, 0x124);  // row_ror:4
      DPPADD(v, 0x128);  // row_ror:8
      acc[j] = v;
    }

    // select my output's sum
    float s = acc[0];
    s = (jm == 1) ? acc[1] : s;
    s = (jm == 2) ? acc[2] : s;
    s = (jm == 3) ? acc[3] : s;
    s += pre_c;
    hn = ftanh(s);
    if (kc < 4){
      hbuf[(((tl & 1) ^ 1) << 8) + wrw] = hn;
      out[(size_t)(b * TC + tl) * HH + o_mine] = hn;
    }
    pre_c = pre_n;
    __syncthreads();
  }
  if (kc < 4) hst[(size_t)b * HH + o_mine] = hn;
}

// ---------------- tiled fp32 GEMM tile (128x128, K=256) ----------------
__device__ __forceinline__ void gemm_tile(
  const float* __restrict__ A, const float* __restrict__ Bw,
  const float* __restrict__ bias, float* __restrict__ C,
  int bx, int by)
{
  __shared__ float As[16][132];
  __shared__ float Bs[16][132];
  const int tid = threadIdx.x;
  const int tx = tid & 15, ty = tid >> 4;
  const size_t n0 = (size_t)bx * 128;
  const int c0 = by * 128;
  float acc[8][8];
  #pragma unroll
  for (int i = 0; i < 8; ++i)
    #pragma unroll
    for (int j = 0; j < 8; ++j) acc[i][j] = 0.f;

  for (int k0 = 0; k0 < 256; k0 += 16){
    #pragma unroll
    for (int q = 0; q < 2; ++q){
      int f = tid + q*256;
      int row = f >> 2, k4 = f & 3;
      float4 va = *(const float4*)(A + (n0 + row)*256 + k0 + k4*4);
      As[k4*4+0][row] = va.x; As[k4*4+1][row] = va.y; As[k4*4+2][row] = va.z; As[k4*4+3][row] = va.w;
      float4 vb = *(const float4*)(Bw + (size_t)(c0 + row)*256 + k0 + k4*4);
      Bs[k4*4+0][row] = vb.x; Bs[k4*4+1][row] = vb.y; Bs[k4*4+2][row] = vb.z; Bs[k4*4+3][row] = vb.w;
    }
    __syncthreads();
    #pragma unroll
    for (int k = 0; k < 16; ++k){
      float a[8], bb[8];
      *(float4*)&a[0]  = *(const float4*)&As[k][ty*4];
      *(float4*)&a[4]  = *(const float4*)&As[k][ty*4 + 64];
      *(float4*)&bb[0] = *(const float4*)&Bs[k][tx*4];
      *(float4*)&bb[4] = *(const float4*)&Bs[k][tx*4 + 64];
      #pragma unroll
      for (int i = 0; i < 8; ++i)
        #pragma unroll
        for (int j = 0; j < 8; ++j) acc[i][j] = fmaf(a[i], bb[j], acc[i][j]);
    }
    __syncthreads();
  }
  #pragma unroll
  for (int i = 0; i < 8; ++i){
    size_t row = n0 + (size_t)ty*4 + (i & 3) + (i >> 2)*64;
    #pragma unroll
    for (int jh = 0; jh < 2; ++jh){
      int col = c0 + tx*4 + jh*64;
      float4 v;
      v.x = acc[i][jh*4+0] + bias[col+0];
      v.y = acc[i][jh*4+1] + bias[col+1];
      v.z = acc[i][jh*4+2] + bias[col+2];
      v.w = acc[i][jh*4+3] + bias[col+3];
      *(float4*)(C + row * 256 + col) = v;
    }
  }
}

// ---------------- head tile: gelu(A@qWh1^T + bh1) @ qWh2 + bh2 -> y ----------------
__device__ __forceinline__ void head_tile(
  const float* __restrict__ A, const float* __restrict__ Bw,
  const float* __restrict__ bh1, const float* __restrict__ w2,
  const float* __restrict__ bh2, float* __restrict__ y,
  int bx, int c2)
{
  __shared__ float As[16][132];
  __shared__ float Bs[16][132];
  const int tid = threadIdx.x;
  const int tx = tid & 15, ty = tid >> 4;
  const size_t n0 = (size_t)bx * 128;
  float acc[8][8];
  #pragma unroll
  for (int i = 0; i < 8; ++i)
    #pragma unroll
    for (int j = 0; j < 8; ++j) acc[i][j] = 0.f;

  for (int k0 = 0; k0 < 256; k0 += 16){
    #pragma unroll
    for (int q = 0; q < 2; ++q){
      int f = tid + q*256;
      int row = f >> 2, k4 = f & 3;
      float4 va = *(const float4*)(A + (n0 + row)*256 + k0 + k4*4);
      As[k4*4+0][row] = va.x; As[k4*4+1][row] = va.y; As[k4*4+2][row] = va.z; As[k4*4+3][row] = va.w;
      float4 vb = *(const float4*)(Bw + (size_t)row*256 + k0 + k4*4);   // 128 rows
      Bs[k4*4+0][row] = vb.x; Bs[k4*4+1][row] = vb.y; Bs[k4*4+2][row] = vb.z; Bs[k4*4+3][row] = vb.w;
    }
    __syncthreads();
    #pragma unroll
    for (int k = 0; k < 16; ++k){
      float a[8], bb[8];
      *(float4*)&a[0]  = *(const float4*)&As[k][ty*4];
      *(float4*)&a[4]  = *(const float4*)&As[k][ty*4 + 64];
      *(float4*)&bb[0] = *(const float4*)&Bs[k][tx*4];
      *(float4*)&bb[4] = *(const float4*)&Bs[k][tx*4 + 64];
      #pragma unroll
      for (int i = 0; i < 8; ++i)
        #pragma unroll
        for (int j = 0; j < 8; ++j) acc[i][j] = fmaf(a[i], bb[j], acc[i][j]);
    }
    __syncthreads();
  }
  float4 w2a = *(const float4*)(w2 + tx*4);
  float4 w2b = *(const float4*)(w2 + tx*4 + 64);
  const float bias2 = bh2[0];
  #pragma unroll
  for (int i = 0; i < 8; ++i){
    float p = 0.f;
    #pragma unroll
    for (int j = 0; j < 4; ++j){
      float g0 = acc[i][j]   + bh1[tx*4 + j];
      float g1 = acc[i][4+j] + bh1[tx*4 + 64 + j];
      g0 = 0.5f * g0 * (1.f + erff(g0 * 0.70710678118654752f));
      g1 = 0.5f * g1 * (1.f + erff(g1 * 0.70710678118654752f));
      p = fmaf(g0, ((const float*)&w2a)[j], p);
      p = fmaf(g1, ((const float*)&w2b)[j], p);
    }
    // reduce across the 16 tx lanes (row_shr chain); total at tx==15
    p += __int_as_float(__builtin_amdgcn_update_dpp(0, __float_as_int(p), 0x111, 0xF, 0xF, true));
    p += __int_as_float(__builtin_amdgcn_update_dpp(0, __float_as_int(p), 0x112, 0xF, 0xF, true));
    p += __int_as_float(__builtin_amdgcn_update_dpp(0, __float_as_int(p), 0x114, 0xF, 0xF, true));
    p += __int_as_float(__builtin_amdgcn_update_dpp(0, __float_as_int(p), 0x118, 0xF, 0xF, true));
    if (tx == 15){
      size_t n = n0 + (size_t)ty*4 + (i & 3) + (i >> 2)*64;
      int bsm = (int)(n >> 9);
      int tl  = (int)(n & (TC - 1));
      y[(size_t)bsm * TT + c2 * TC + tl] = p + bias2;
    }
  }
}

// ---------------- per-slot aux: gemm1 + gemm2 + head (fused GEMV) ----------------
__global__ __launch_bounds__(256) void aux_kernel(
  const float* __restrict__ out0, const float* __restrict__ out1, const float* __restrict__ out2,
  const float* __restrict__ wih1, const float* __restrict__ bL1, float* __restrict__ pre1,
  const float* __restrict__ wih2, const float* __restrict__ bL2, float* __restrict__ pre2,
  const float* __restrict__ qWh1, const float* __restrict__ bh1,
  const float* __restrict__ qWh2, const float* __restrict__ bh2,
  float* __restrict__ y, int slot)
{
  const int bid = blockIdx.x;
  if (bid < 512){
    int sec = bid >> 8;          // 0: pre1 from out0; 1: pre2 from out1
    int c = slot - sec;
    if (c < 0 || c >= NCH) return;
    int t = bid & 255;
    if (sec == 0) gemm_tile(out0, wih1, bL1, pre1, t >> 1, t & 1);
    else          gemm_tile(out1, wih2, bL2, pre2, t >> 1, t & 1);
  } else {
    int c2 = slot - 2;
    if (c2 < 0 || c2 >= NCH) return;
    head_tile(out2, qWh1, bh1, qWh2, bh2, y, bid - 512, c2);
  }
}

extern "C" void kernel_launch(void* const* d_in, const int* in_sizes, int n_in,
                              void* d_out, int out_size, void* d_ws, size_t ws_size,
                              hipStream_t stream)
{
  const float* x    = (const float*)d_in[0];
  const float* W1   = (const float*)d_in[1];
  const float* b1   = (const float*)d_in[2];
  const float* W2   = (const float*)d_in[3];
  const float* b2   = (const float*)d_in[4];
  const float* wih0 = (const float*)d_in[5];
  const float* whh0 = (const float*)d_in[6];
  const float* bih0 = (const float*)d_in[7];
  const float* bhh0 = (const float*)d_in[8];
  const float* wih1 = (const float*)d_in[9];
  const float* whh1 = (const float*)d_in[10];
  const float* bih1 = (const float*)d_in[11];
  const float* bhh1 = (const float*)d_in[12];
  const float* wih2 = (const float*)d_in[13];
  const float* whh2 = (const float*)d_in[14];
  const float* bih2 = (const float*)d_in[15];
  const float* bhh2 = (const float*)d_in[16];
  const float* Wh1  = (const float*)d_in[17];
  const float* bh1  = (const float*)d_in[18];
  const float* Wh2  = (const float*)d_in[19];
  const float* bh2  = (const float*)d_in[20];
  float* y = (float*)d_out;
  (void)in_sizes; (void)n_in; (void)out_size; (void)ws_size;

  char* p = (char*)d_ws;
  auto alloc = [&](size_t nfloats) -> float* {
    float* r = (float*)p;
    p += ((nfloats * sizeof(float) + 255) & ~(size_t)255);
    return r;
  };
  float* qW1  = alloc(576);
  float* qW2  = alloc(2048);
  float* qWh1 = alloc(32768);
  float* qWh2 = alloc(128);
  float* bL1  = alloc(256);
  float* bL2  = alloc(256);
  float* cvec = alloc((size_t)BB * HH);
  float* hst0 = alloc((size_t)BB * HH);
  float* hst1 = alloc((size_t)BB * HH);
  float* hst2 = alloc((size_t)BB * HH);
  float* out0 = alloc((size_t)CROWS * HH);
  float* out1 = alloc((size_t)CROWS * HH);
  float* out2 = alloc((size_t)CROWS * HH);
  float* pre1 = alloc((size_t)CROWS * HH);
  float* pre2 = alloc((size_t)CROWS * HH);

  quant_all<<<141, 256, 0, stream>>>(W1, W2, Wh1, Wh2,
                                     bih1, bhh1, bih2, bhh2,
                                     qW1, qW2, qWh1, qWh2, bL1, bL2);
  ctx_kernel<<<1, 256, 0, stream>>>(x, qW1, b1, qW2, b2, wih0, bih0, bhh0, cvec);

  for (int s = 0; s < NSLOT; ++s){
    scan3<<<96, 1024, 0, stream>>>(whh0, whh1, whh2, pre1, pre2, x, cvec, wih0,
                                   out0, out1, out2, hst0, hst1, hst2, s);
    aux_kernel<<<640, 256, 0, stream>>>(out0, out1, out2,
                                        wih1, bL1, pre1,
                                        wih2, bL2, pre2,
                                        qWh1, bh1, qWh2, bh2, y, s);
  }
}